// Round 8
// baseline (434.595 us; speedup 1.0000x reference)
//
#include <hip/hip_runtime.h>
#include <hip/hip_bf16.h>

#define N_NODES 20000
#define NEDGE   320000
#define DIM     128
#define NH      4
#define HD      512   // NH*DIM
#define LAYERS  3
#define EPS_RMS 1.1920929e-07f
#define SLOPE   0.2f
#define DEGCAP  128
#define NTILES  (N_NODES >> 4)   // 1250

typedef __bf16 bf16_t;
typedef __bf16 bf16v2 __attribute__((ext_vector_type(2)));
typedef __bf16 bf16v8 __attribute__((ext_vector_type(8)));
typedef float  f32v4  __attribute__((ext_vector_type(4)));
typedef float  f32v2  __attribute__((ext_vector_type(2)));

__device__ __forceinline__ int clamp_node(int s) {
    return ((unsigned)s >= (unsigned)N_NODES) ? 0 : s;
}
__device__ __forceinline__ float leaky(float e) { return e > 0.f ? e : SLOPE * e; }
__device__ __forceinline__ unsigned char enc_fp8(float v) {
    int p = __builtin_amdgcn_cvt_pk_fp8_f32(v, v, 0, false);
    return (unsigned char)(p & 0xff);
}
__device__ __forceinline__ unsigned short enc_fp8_pair(float a, float b) {
    int p = __builtin_amdgcn_cvt_pk_fp8_f32(a, b, 0, false);
    return (unsigned short)(p & 0xffff);
}

// ---- per-wave dtype detection ----
__device__ __forceinline__ bool wave_detect_bf16(const unsigned short* xh) {
    int lane = threadIdx.x & 63;
    unsigned short hw = xh[2 * lane];
    int e = (hw >> 7) & 0xff;
    unsigned long long b = __ballot(e >= 96 && e <= 140);
    return __popcll(b) >= 48;
}
__device__ __forceinline__ bool wave_detect_i64(const int* ei) {
    int lane = threadIdx.x & 63;
    unsigned long long b = __ballot(ei[2 * lane + 1] != 0);
    return b == 0ULL;
}
__device__ __forceinline__ float raw_elem(const void* in, size_t j, bool isbf) {
    return isbf ? (float)((const bf16_t*)in)[j] : ((const float*)in)[j];
}
__device__ __forceinline__ bf16_t cvt_elem(const void* in, size_t j, bool isbf) {
    return isbf ? ((const bf16_t*)in)[j] : (bf16_t)((const float*)in)[j];
}
__device__ __forceinline__ int edge_src(const int* ei, int e, bool is64) {
    return clamp_node(is64 ? ei[2 * e] : ei[e]);
}
__device__ __forceinline__ int edge_dst(const int* ei, int e, bool is64) {
    return clamp_node(is64 ? ei[2 * NEDGE + 2 * e] : ei[NEDGE + e]);
}

// ---------------- prep_v: v_s/v_d[l][h][k] = sum_c Wg[l][k][h*128+c] * att[l][h][c] ----------------
// 3072 wave-outputs: w = [l][k][h][sd]
__global__ __launch_bounds__(256) void prep_v(const void* x, const void* Wg,
                                              const void* aS, const void* aD,
                                              float* __restrict__ vS, float* __restrict__ vD) {
    bool isbf = wave_detect_bf16((const unsigned short*)x);
    int w = (int)((blockIdx.x * blockDim.x + threadIdx.x) >> 6);
    if (w >= LAYERS * DIM * NH * 2) return;
    int lane = threadIdx.x & 63;
    int sd = w & 1, h = (w >> 1) & 3, k = (w >> 3) & 127, l = w >> 10;
    const void* att = sd ? aD : aS;
    size_t wbase = (size_t)l * DIM * HD + (size_t)k * HD + h * DIM;
    size_t abase = (size_t)l * NH * DIM + (size_t)h * DIM;
    int c = 2 * lane;
    float p = raw_elem(Wg, wbase + c, isbf) * raw_elem(att, abase + c, isbf)
            + raw_elem(Wg, wbase + c + 1, isbf) * raw_elem(att, abase + c + 1, isbf);
#pragma unroll
    for (int msk = 1; msk < 64; msk <<= 1) p += __shfl_xor(p, msk);
    if (lane == 0) {
        float* dst = sd ? vD : vS;
        dst[l * HD + h * DIM + k] = p;
    }
}

// ---------------- canonicalization (+ hist fused as trailing blocks) ----------------
// WmixT[l][c][h*128+k] = Wg[l][k][h*128+c]  (so x_att = 0.25 * y @ WmixT^T)
__global__ __launch_bounds__(256) void convert_hist(
        const void* x, const void* Wg, const void* W1, const void* W2,
        const void* bg, const void* b1, const void* b2, const void* n1, const void* n2,
        bf16_t* xb, bf16_t* WmixT, bf16_t* W1T, bf16_t* W2T,
        bf16_t* bgc, bf16_t* b1c, bf16_t* b2c, bf16_t* n1c, bf16_t* n2c,
        const int* ei, int* deg, int convBlocks) {
    const int NX  = N_NODES * DIM;
    const int NWG = LAYERS * DIM * HD;
    const int NW1 = LAYERS * DIM * DIM;
    const int NV  = LAYERS * DIM;
    if ((int)blockIdx.x >= convBlocks) {
        bool is64 = wave_detect_i64(ei);
        int e = ((int)blockIdx.x - convBlocks) * 256 + threadIdx.x;
        if (e < NEDGE) atomicAdd(&deg[edge_dst(ei, e, is64)], 1);
        return;
    }
    bool isbf = wave_detect_bf16((const unsigned short*)x);
    int i = blockIdx.x * blockDim.x + threadIdx.x;
    if (i < NX) { xb[i] = cvt_elem(x, i, isbf); return; }
    i -= NX;
    if (i < NWG) {
        int l = i / (DIM * HD);
        int rem = i - l * (DIM * HD);
        int c = rem / HD, kp = rem - c * HD;
        int h = kp >> 7, k = kp & 127;
        WmixT[i] = cvt_elem(Wg, (size_t)l * DIM * HD + (size_t)k * HD + h * DIM + c, isbf);
        return;
    }
    i -= NWG;
    if (i < NW1) {
        int l = i / (DIM * DIM);
        int rem = i - l * (DIM * DIM);
        int c = rem / DIM, k = rem - c * DIM;
        W1T[i] = cvt_elem(W1, (size_t)l * DIM * DIM + (size_t)k * DIM + c, isbf);
        return;
    }
    i -= NW1;
    if (i < NW1) {
        int l = i / (DIM * DIM);
        int rem = i - l * (DIM * DIM);
        int c = rem / DIM, k = rem - c * DIM;
        W2T[i] = cvt_elem(W2, (size_t)l * DIM * DIM + (size_t)k * DIM + c, isbf);
        return;
    }
    i -= NW1;
    if (i >= 5 * NV) return;
    int seg = i / NV, k = i - seg * NV;
    if (seg == 0) bgc[k] = cvt_elem(bg, k, isbf);
    else if (seg == 1) b1c[k] = cvt_elem(b1, k, isbf);
    else if (seg == 2) b2c[k] = cvt_elem(b2, k, isbf);
    else if (seg == 3) n1c[k] = cvt_elem(n1, k, isbf);
    else n2c[k] = cvt_elem(n2, k, isbf);
}

__global__ __launch_bounds__(1024) void scan_kernel(const int* __restrict__ deg,
                                                    int* __restrict__ row_ptr,
                                                    int* __restrict__ cursor) {
    __shared__ int wsum[16];
    __shared__ int carry_s;
    int tid = threadIdx.x, lane = tid & 63, wv = tid >> 6;
    if (tid == 0) { carry_s = 0; row_ptr[0] = 0; }
    __syncthreads();
    for (int base = 0; base < N_NODES; base += 1024) {
        int idx = base + tid;
        int v = (idx < N_NODES) ? deg[idx] : 0;
        int x = v;
#pragma unroll
        for (int off = 1; off < 64; off <<= 1) {
            int t = __shfl_up(x, off);
            if (lane >= off) x += t;
        }
        if (lane == 63) wsum[wv] = x;
        __syncthreads();
        if (wv == 0) {
            int s = (lane < 16) ? wsum[lane] : 0;
#pragma unroll
            for (int off = 1; off < 16; off <<= 1) {
                int t = __shfl_up(s, off);
                if (lane >= off) s += t;
            }
            if (lane < 16) wsum[lane] = s;
        }
        __syncthreads();
        int woff = (wv == 0) ? 0 : wsum[wv - 1];
        int c = carry_s;
        int incl = x + woff + c;
        if (idx < N_NODES) {
            row_ptr[idx + 1] = incl;
            cursor[idx] = incl - v;
        }
        __syncthreads();
        if (tid == 1023) carry_s = incl;
        __syncthreads();
    }
}

__global__ void fill_kernel(const int* __restrict__ ei, int* __restrict__ cursor,
                            int* __restrict__ csr_src) {
    bool is64 = wave_detect_i64(ei);
    int e = blockIdx.x * blockDim.x + threadIdx.x;
    if (e < NEDGE) {
        int d = edge_dst(ei, e, is64);
        int pos = atomicAdd(&cursor[d], 1);
        if ((unsigned)pos < (unsigned)NEDGE) csr_src[pos] = edge_src(ei, e, is64);
    }
}

// ---------------- asd_x8 (layer 0): a_s/a_d = x·v, x8 = fp8(x). one wave/node ----------------
__global__ __launch_bounds__(256) void asd_x8(const bf16_t* __restrict__ xb,
                                              const float* __restrict__ vS,
                                              const float* __restrict__ vD,
                                              float* __restrict__ a_s,
                                              float* __restrict__ a_d,
                                              unsigned short* __restrict__ x8) {
    int n = (int)((blockIdx.x * blockDim.x + threadIdx.x) >> 6);
    if (n >= N_NODES) return;
    int lane = threadIdx.x & 63;
    int c = 2 * lane;
    bf16v2 xv = *reinterpret_cast<const bf16v2*>(xb + (size_t)n * DIM + c);
    float f0 = (float)xv[0], f1 = (float)xv[1];
    x8[n * 64 + lane] = enc_fp8_pair(f0, f1);
#pragma unroll
    for (int h = 0; h < NH; ++h) {
        float ps = f0 * vS[h * DIM + c] + f1 * vS[h * DIM + c + 1];
        float pd = f0 * vD[h * DIM + c] + f1 * vD[h * DIM + c + 1];
#pragma unroll
        for (int msk = 1; msk < 64; msk <<= 1) {
            ps += __shfl_xor(ps, msk);
            pd += __shfl_xor(pd, msk);
        }
        if (lane == 0) {
            a_s[n * 4 + h] = ps;
            a_d[n * 4 + h] = pd;
        }
    }
}

// ---------------- gat_gather: y[n, h*128+k] = (1/Z_h) sum_e alpha_eh * x8[s,k] ----------------
__global__ __launch_bounds__(256) void gat_gather(const int* __restrict__ row_ptr,
                                                  const int* __restrict__ csr_src,
                                                  const float* __restrict__ a_s,
                                                  const float* __restrict__ a_d,
                                                  const unsigned short* __restrict__ x8,
                                                  bf16_t* __restrict__ y) {
    __shared__ float4 wlds[4][DEGCAP];
    int n = (int)((blockIdx.x * blockDim.x + threadIdx.x) >> 6);
    if (n >= N_NODES) return;
    int lane = threadIdx.x & 63;
    int wv = threadIdx.x >> 6;
    int beg = row_ptr[n];
    int deg = row_ptr[n + 1] - beg;
    if (deg < 0) deg = 0;
    if (deg > NEDGE) deg = NEDGE;
    if (beg < 0) beg = 0;
    if (beg > NEDGE - deg) beg = NEDGE - deg;

    const float4* a_s4 = reinterpret_cast<const float4*>(a_s);
    const float4 adv = reinterpret_cast<const float4*>(a_d)[n];
    const float4 avs = a_s4[n];
    unsigned short pself = x8[n * 64 + lane];
    int s_reg = (lane < deg) ? clamp_node(csr_src[beg + lane]) : n;

    float4 ev_self = {leaky(avs.x + adv.x), leaky(avs.y + adv.y),
                      leaky(avs.z + adv.z), leaky(avs.w + adv.w)};
    float4 m4 = ev_self;
    for (int i = lane; i < deg; i += 64) {
        int s = (i == lane) ? s_reg : clamp_node(csr_src[beg + i]);
        float4 av = a_s4[s];
        float4 ev = {leaky(av.x + adv.x), leaky(av.y + adv.y),
                     leaky(av.z + adv.z), leaky(av.w + adv.w)};
        if (i < DEGCAP) wlds[wv][i] = ev;
        m4.x = fmaxf(m4.x, ev.x); m4.y = fmaxf(m4.y, ev.y);
        m4.z = fmaxf(m4.z, ev.z); m4.w = fmaxf(m4.w, ev.w);
    }
#pragma unroll
    for (int msk = 1; msk < 64; msk <<= 1) {
        m4.x = fmaxf(m4.x, __shfl_xor(m4.x, msk));
        m4.y = fmaxf(m4.y, __shfl_xor(m4.y, msk));
        m4.z = fmaxf(m4.z, __shfl_xor(m4.z, msk));
        m4.w = fmaxf(m4.w, __shfl_xor(m4.w, msk));
    }
    float4 s4 = {0.f, 0.f, 0.f, 0.f};
    for (int i = lane; i < deg; i += 64) {
        float4 ev;
        if (i < DEGCAP) ev = wlds[wv][i];
        else {
            int s = clamp_node(csr_src[beg + i]);
            float4 av = a_s4[s];
            ev = {leaky(av.x + adv.x), leaky(av.y + adv.y),
                  leaky(av.z + adv.z), leaky(av.w + adv.w)};
        }
        float4 ex = {__expf(ev.x - m4.x), __expf(ev.y - m4.y),
                     __expf(ev.z - m4.z), __expf(ev.w - m4.w)};
        if (i < DEGCAP) wlds[wv][i] = ex;
        s4.x += ex.x; s4.y += ex.y; s4.z += ex.z; s4.w += ex.w;
    }
#pragma unroll
    for (int msk = 1; msk < 64; msk <<= 1) {
        s4.x += __shfl_xor(s4.x, msk);
        s4.y += __shfl_xor(s4.y, msk);
        s4.z += __shfl_xor(s4.z, msk);
        s4.w += __shfl_xor(s4.w, msk);
    }
    float4 exs = {__expf(ev_self.x - m4.x), __expf(ev_self.y - m4.y),
                  __expf(ev_self.z - m4.z), __expf(ev_self.w - m4.w)};
    s4.x += exs.x; s4.y += exs.y; s4.z += exs.z; s4.w += exs.w;
    float4 ih4 = {1.f / s4.x, 1.f / s4.y, 1.f / s4.z, 1.f / s4.w};

    // accumulate: acc[h*2+j] over shared decoded x dims (2 per lane)
    float acc[8];
    {
        f32v2 f = __builtin_amdgcn_cvt_pk_f32_fp8((int)pself, false);
        acc[0] = exs.x * f[0]; acc[1] = exs.x * f[1];
        acc[2] = exs.y * f[0]; acc[3] = exs.y * f[1];
        acc[4] = exs.z * f[0]; acc[5] = exs.z * f[1];
        acc[6] = exs.w * f[0]; acc[7] = exs.w * f[1];
    }
    for (int b0 = 0; b0 < deg; b0 += 4) {
        int cnt = deg - b0; if (cnt > 4) cnt = 4;
        unsigned short xe[4]; float4 w4[4];
#pragma unroll
        for (int u = 0; u < 4; ++u) {
            if (u < cnt) {
                int e = b0 + u;
                int s = (e < 64) ? __shfl(s_reg, e) : clamp_node(csr_src[beg + e]);
                xe[u] = x8[s * 64 + lane];
                if (e < DEGCAP) w4[u] = wlds[wv][e];
                else {
                    float4 av = a_s4[s];
                    w4[u] = {__expf(leaky(av.x + adv.x) - m4.x),
                             __expf(leaky(av.y + adv.y) - m4.y),
                             __expf(leaky(av.z + adv.z) - m4.z),
                             __expf(leaky(av.w + adv.w) - m4.w)};
                }
            }
        }
#pragma unroll
        for (int u = 0; u < 4; ++u) {
            if (u < cnt) {
                f32v2 f = __builtin_amdgcn_cvt_pk_f32_fp8((int)xe[u], false);
                acc[0] += w4[u].x * f[0]; acc[1] += w4[u].x * f[1];
                acc[2] += w4[u].y * f[0]; acc[3] += w4[u].y * f[1];
                acc[4] += w4[u].z * f[0]; acc[5] += w4[u].z * f[1];
                acc[6] += w4[u].w * f[0]; acc[7] += w4[u].w * f[1];
            }
        }
    }
    int c = 2 * lane;
#pragma unroll
    for (int h = 0; h < NH; ++h) {
        float ih = h == 0 ? ih4.x : h == 1 ? ih4.y : h == 2 ? ih4.z : ih4.w;
        bf16v2 o;
        o[0] = (bf16_t)(acc[h * 2 + 0] * ih);
        o[1] = (bf16_t)(acc[h * 2 + 1] * ih);
        *reinterpret_cast<bf16v2*>(y + (size_t)n * HD + h * DIM + c) = o;
    }
}

// ---------------- gemm_mix: xmid = rmsnorm(xb + 0.25*y@Wmix + bias_g, n1w) ----------------
// one wave = 16 rows x 128 cols, K=512
__global__ __launch_bounds__(256) void gemm_mix(const bf16_t* __restrict__ y,
                                                const bf16_t* __restrict__ Bt,
                                                const bf16_t* __restrict__ bias,
                                                const bf16_t* __restrict__ res,
                                                const bf16_t* __restrict__ normw,
                                                bf16_t* __restrict__ xmid) {
    int unit = (int)((blockIdx.x * blockDim.x + threadIdx.x) >> 6);
    if (unit >= NTILES) return;
    int lane = threadIdx.x & 63;
    int m = lane & 15, kq = lane >> 4;

    f32v4 acc[8];
#pragma unroll
    for (int t = 0; t < 8; ++t) acc[t] = (f32v4){0.f, 0.f, 0.f, 0.f};
    const bf16_t* Arow = y + (size_t)(unit * 16 + m) * HD + kq * 8;
    const bf16_t* Bbase = Bt + (size_t)m * HD + kq * 8;
#pragma unroll
    for (int kb = 0; kb < 4; ++kb) {
        bf16v8 a[4];
#pragma unroll
        for (int ks = 0; ks < 4; ++ks)
            a[ks] = *reinterpret_cast<const bf16v8*>(Arow + kb * 128 + ks * 32);
#pragma unroll
        for (int ks = 0; ks < 4; ++ks) {
#pragma unroll
            for (int t = 0; t < 8; ++t) {
                bf16v8 b = *reinterpret_cast<const bf16v8*>(Bbase + (size_t)t * 16 * HD + kb * 128 + ks * 32);
                acc[t] = __builtin_amdgcn_mfma_f32_16x16x32_bf16(a[ks], b, acc[t], 0, 0, 0);
            }
        }
    }
    int growbase = unit * 16 + kq * 4;
    float vals[8][4];
    float ssq[4] = {0.f, 0.f, 0.f, 0.f};
#pragma unroll
    for (int t = 0; t < 8; ++t) {
        int col = t * 16 + m;
        float bv = (float)bias[col];
#pragma unroll
        for (int r = 0; r < 4; ++r) {
            float v = 0.25f * acc[t][r] + bv + (float)res[(size_t)(growbase + r) * DIM + col];
            vals[t][r] = v;
            ssq[r] += v * v;
        }
    }
#pragma unroll
    for (int r = 0; r < 4; ++r) {
        float s = ssq[r];
        s += __shfl_xor(s, 1); s += __shfl_xor(s, 2);
        s += __shfl_xor(s, 4); s += __shfl_xor(s, 8);
        ssq[r] = rsqrtf(s * (1.f / 128.f) + EPS_RMS);
    }
#pragma unroll
    for (int t = 0; t < 8; ++t) {
        int col = t * 16 + m;
        float nwv = (float)normw[col];
#pragma unroll
        for (int r = 0; r < 4; ++r)
            xmid[(size_t)(growbase + r) * DIM + col] = (bf16_t)(vals[t][r] * ssq[r] * nwv);
    }
}

// ---------------- fused FFN (+ next-layer asd/x8 for MODE 0) ----------------
// MODE 0: write bf16 xb + a_s/a_d/x8 for next layer. MODE 1: write f32 d_out.
template <int MODE>
__global__ __launch_bounds__(256) void ffn_fused(const bf16_t* __restrict__ A,
                                                 const bf16_t* __restrict__ B1t,
                                                 const bf16_t* __restrict__ b1,
                                                 const bf16_t* __restrict__ B2t,
                                                 const bf16_t* __restrict__ b2,
                                                 const bf16_t* __restrict__ nw,
                                                 void* __restrict__ Cout,
                                                 const float* __restrict__ vS,
                                                 const float* __restrict__ vD,
                                                 float* __restrict__ a_s,
                                                 float* __restrict__ a_d,
                                                 unsigned char* __restrict__ x8) {
    __shared__ bf16_t hl[4][16 * 136];
    int unit = (int)((blockIdx.x * blockDim.x + threadIdx.x) >> 6);
    if (unit >= NTILES) return;
    int lane = threadIdx.x & 63;
    int wv = threadIdx.x >> 6;
    int m = lane & 15, kq = lane >> 4;

    const bf16_t* Arow = A + (size_t)(unit * 16 + m) * DIM + kq * 8;
    bf16v8 a[4];
#pragma unroll
    for (int ks = 0; ks < 4; ++ks)
        a[ks] = *reinterpret_cast<const bf16v8*>(Arow + ks * 32);
    f32v4 acc[8];
#pragma unroll
    for (int t = 0; t < 8; ++t) acc[t] = (f32v4){0.f, 0.f, 0.f, 0.f};
    const bf16_t* Bb1 = B1t + (size_t)m * DIM + kq * 8;
#pragma unroll
    for (int ks = 0; ks < 4; ++ks) {
#pragma unroll
        for (int t = 0; t < 8; ++t) {
            bf16v8 b = *reinterpret_cast<const bf16v8*>(Bb1 + (size_t)t * 16 * DIM + ks * 32);
            acc[t] = __builtin_amdgcn_mfma_f32_16x16x32_bf16(a[ks], b, acc[t], 0, 0, 0);
        }
    }
#pragma unroll
    for (int t = 0; t < 8; ++t) {
        int col = t * 16 + m;
        float bv = (float)b1[col];
#pragma unroll
        for (int r = 0; r < 4; ++r) {
            float v = acc[t][r] + bv;
            v = v > 0.f ? v : 0.f;
            hl[wv][(kq * 4 + r) * 136 + col] = (bf16_t)v;
        }
    }
    bf16v8 a2[4];
#pragma unroll
    for (int ks = 0; ks < 4; ++ks)
        a2[ks] = *reinterpret_cast<const bf16v8*>(&hl[wv][m * 136 + ks * 32 + kq * 8]);
    f32v4 acc2[8];
#pragma unroll
    for (int t = 0; t < 8; ++t) acc2[t] = (f32v4){0.f, 0.f, 0.f, 0.f};
    const bf16_t* Bb2 = B2t + (size_t)m * DIM + kq * 8;
#pragma unroll
    for (int ks = 0; ks < 4; ++ks) {
#pragma unroll
        for (int t = 0; t < 8; ++t) {
            bf16v8 b = *reinterpret_cast<const bf16v8*>(Bb2 + (size_t)t * 16 * DIM + ks * 32);
            acc2[t] = __builtin_amdgcn_mfma_f32_16x16x32_bf16(a2[ks], b, acc2[t], 0, 0, 0);
        }
    }
    int growbase = unit * 16 + kq * 4;
    float vals[8][4];
    float ssq[4] = {0.f, 0.f, 0.f, 0.f};
#pragma unroll
    for (int t = 0; t < 8; ++t) {
        int col = t * 16 + m;
        float bv = (float)b2[col];
#pragma unroll
        for (int r = 0; r < 4; ++r) {
            float v = acc2[t][r] + bv + (float)A[(size_t)(growbase + r) * DIM + col];
            vals[t][r] = v;
            ssq[r] += v * v;
        }
    }
#pragma unroll
    for (int r = 0; r < 4; ++r) {
        float s = ssq[r];
        s += __shfl_xor(s, 1); s += __shfl_xor(s, 2);
        s += __shfl_xor(s, 4); s += __shfl_xor(s, 8);
        ssq[r] = rsqrtf(s * (1.f / 128.f) + EPS_RMS);
    }
    float ox[8][4];
#pragma unroll
    for (int t = 0; t < 8; ++t) {
        int col = t * 16 + m;
        float nwv = (float)nw[col];
#pragma unroll
        for (int r = 0; r < 4; ++r) {
            float o = vals[t][r] * ssq[r] * nwv;
            ox[t][r] = o;
            if (MODE == 1) ((float*)Cout)[(size_t)(growbase + r) * DIM + col] = o;
            else           ((bf16_t*)Cout)[(size_t)(growbase + r) * DIM + col] = (bf16_t)o;
        }
    }
    if (MODE == 0) {
        // next-layer attention coefficients + fp8 copy
#pragma unroll
        for (int t = 0; t < 8; ++t) {
            int col = t * 16 + m;
#pragma unroll
            for (int r = 0; r < 4; ++r)
                x8[(size_t)(growbase + r) * DIM + col] = enc_fp8(ox[t][r]);
        }
#pragma unroll
        for (int r = 0; r < 4; ++r) {
#pragma unroll
            for (int h = 0; h < NH; ++h) {
                float ps = 0.f, pd = 0.f;
#pragma unroll
                for (int t = 0; t < 8; ++t) {
                    int col = t * 16 + m;
                    ps += ox[t][r] * vS[h * DIM + col];
                    pd += ox[t][r] * vD[h * DIM + col];
                }
                ps += __shfl_xor(ps, 1); ps += __shfl_xor(ps, 2);
                ps += __shfl_xor(ps, 4); ps += __shfl_xor(ps, 8);
                pd += __shfl_xor(pd, 1); pd += __shfl_xor(pd, 2);
                pd += __shfl_xor(pd, 4); pd += __shfl_xor(pd, 8);
                if (m == 0) {
                    int row = growbase + r;
                    a_s[row * 4 + h] = ps;
                    a_d[row * 4 + h] = pd;
                }
            }
        }
    }
}

// ---------------- launch ----------------
extern "C" void kernel_launch(void* const* d_in, const int* in_sizes, int n_in,
                              void* d_out, int out_size, void* d_ws, size_t ws_size,
                              hipStream_t stream) {
    const void* x_in   = d_in[0];
    const void* W_gat  = d_in[1];
    const void* att_s  = d_in[2];
    const void* att_d  = d_in[3];
    const void* bias_g = d_in[4];
    const void* W1     = d_in[5];
    const void* b1     = d_in[6];
    const void* W2     = d_in[7];
    const void* b2     = d_in[8];
    const void* n1w    = d_in[9];
    const void* n2w    = d_in[10];
    const int*  ei     = (const int*)d_in[11];

    char* ws = (char*)d_ws;
    size_t off = 0;
    auto alloc = [&](size_t bytes) {
        void* p = ws + off;
        off = (off + bytes + 255) & ~(size_t)255;
        return p;
    };
    bf16_t* WmixT   = (bf16_t*)alloc((size_t)LAYERS * HD * DIM * 2);
    bf16_t* W1T     = (bf16_t*)alloc((size_t)LAYERS * DIM * DIM * 2);
    bf16_t* W2T     = (bf16_t*)alloc((size_t)LAYERS * DIM * DIM * 2);
    bf16_t* xb      = (bf16_t*)alloc((size_t)N_NODES * DIM * 2);
    bf16_t* y       = (bf16_t*)alloc((size_t)N_NODES * HD * 2);
    unsigned short* x8 = (unsigned short*)alloc((size_t)N_NODES * DIM);
    float*  vS      = (float*)alloc((size_t)LAYERS * HD * 4);
    float*  vD      = (float*)alloc((size_t)LAYERS * HD * 4);
    float*  a_s     = (float*)alloc((size_t)N_NODES * NH * 4);
    float*  a_d     = (float*)alloc((size_t)N_NODES * NH * 4);
    int*    deg     = (int*)alloc((size_t)N_NODES * 4);
    int*    cursor  = (int*)alloc((size_t)N_NODES * 4);
    int*    row_ptr = (int*)alloc((size_t)(N_NODES + 1) * 4);
    int*    csr     = (int*)alloc((size_t)NEDGE * 4);
    bf16_t* xmid    = (bf16_t*)alloc((size_t)N_NODES * DIM * 2);
    bf16_t* bgc     = (bf16_t*)alloc((size_t)LAYERS * DIM * 2);
    bf16_t* b1c     = (bf16_t*)alloc((size_t)LAYERS * DIM * 2);
    bf16_t* b2c     = (bf16_t*)alloc((size_t)LAYERS * DIM * 2);
    bf16_t* n1c     = (bf16_t*)alloc((size_t)LAYERS * DIM * 2);
    bf16_t* n2c     = (bf16_t*)alloc((size_t)LAYERS * DIM * 2);

    hipMemsetAsync(deg, 0, (size_t)N_NODES * 4, stream);

    prep_v<<<(LAYERS * DIM * NH * 2 * 64 + 255) / 256, 256, 0, stream>>>(
        x_in, W_gat, att_s, att_d, vS, vD);

    const int NTOT = N_NODES * DIM + LAYERS * DIM * HD + 2 * LAYERS * DIM * DIM
                   + 5 * LAYERS * DIM;
    const int convBlocks = (NTOT + 255) / 256;
    const int histBlocks = (NEDGE + 255) / 256;
    convert_hist<<<convBlocks + histBlocks, 256, 0, stream>>>(
        x_in, W_gat, W1, W2, bias_g, b1, b2, n1w, n2w,
        xb, WmixT, W1T, W2T, bgc, b1c, b2c, n1c, n2c,
        ei, deg, convBlocks);

    scan_kernel<<<1, 1024, 0, stream>>>(deg, row_ptr, cursor);
    fill_kernel<<<(NEDGE + 255) / 256, 256, 0, stream>>>(ei, cursor, csr);
    asd_x8<<<(N_NODES * 64 + 255) / 256, 256, 0, stream>>>(xb, vS, vD, a_s, a_d, x8);

    for (int l = 0; l < LAYERS; ++l) {
        gat_gather<<<(N_NODES * 64 + 255) / 256, 256, 0, stream>>>(
            row_ptr, csr, a_s, a_d, x8, y);
        gemm_mix<<<(NTILES * 64 + 255) / 256, 256, 0, stream>>>(
            y, WmixT + (size_t)l * HD * DIM, bgc + (size_t)l * DIM,
            xb, n1c + (size_t)l * DIM, xmid);
        if (l < LAYERS - 1) {
            ffn_fused<0><<<(NTILES * 64 + 255) / 256, 256, 0, stream>>>(
                xmid, W1T + (size_t)l * DIM * DIM, b1c + (size_t)l * DIM,
                W2T + (size_t)l * DIM * DIM, b2c + (size_t)l * DIM,
                n2c + (size_t)l * DIM, xb,
                vS + (size_t)(l + 1) * HD, vD + (size_t)(l + 1) * HD,
                a_s, a_d, (unsigned char*)x8);
        } else {
            ffn_fused<1><<<(NTILES * 64 + 255) / 256, 256, 0, stream>>>(
                xmid, W1T + (size_t)l * DIM * DIM, b1c + (size_t)l * DIM,
                W2T + (size_t)l * DIM * DIM, b2c + (size_t)l * DIM,
                n2c + (size_t)l * DIM, d_out,
                nullptr, nullptr, nullptr, nullptr, nullptr);
        }
    }
}

// Round 9
// 399.961 us; speedup vs baseline: 1.0866x; 1.0866x over previous
//
#include <hip/hip_runtime.h>
#include <hip/hip_bf16.h>

#define N_NODES 20000
#define NEDGE   320000
#define DIM     128
#define NH      4
#define HD      512   // NH*DIM
#define LAYERS  3
#define EPS_RMS 1.1920929e-07f
#define SLOPE   0.2f
#define DEGCAP  128
#define NTILES  (N_NODES >> 4)   // 1250

typedef __bf16 bf16_t;
typedef __bf16 bf16v2 __attribute__((ext_vector_type(2)));
typedef __bf16 bf16v8 __attribute__((ext_vector_type(8)));
typedef float  f32v4  __attribute__((ext_vector_type(4)));
typedef float  f32v2  __attribute__((ext_vector_type(2)));

__device__ __forceinline__ int clamp_node(int s) {
    return ((unsigned)s >= (unsigned)N_NODES) ? 0 : s;
}
__device__ __forceinline__ float leaky(float e) { return e > 0.f ? e : SLOPE * e; }
__device__ __forceinline__ unsigned char enc_fp8(float v) {
    int p = __builtin_amdgcn_cvt_pk_fp8_f32(v, v, 0, false);
    return (unsigned char)(p & 0xff);
}
__device__ __forceinline__ unsigned short enc_fp8_pair(float a, float b) {
    int p = __builtin_amdgcn_cvt_pk_fp8_f32(a, b, 0, false);
    return (unsigned short)(p & 0xffff);
}

// ---- per-wave dtype detection ----
__device__ __forceinline__ bool wave_detect_bf16(const unsigned short* xh) {
    int lane = threadIdx.x & 63;
    unsigned short hw = xh[2 * lane];
    int e = (hw >> 7) & 0xff;
    unsigned long long b = __ballot(e >= 96 && e <= 140);
    return __popcll(b) >= 48;
}
__device__ __forceinline__ bool wave_detect_i64(const int* ei) {
    int lane = threadIdx.x & 63;
    unsigned long long b = __ballot(ei[2 * lane + 1] != 0);
    return b == 0ULL;
}
__device__ __forceinline__ float raw_elem(const void* in, size_t j, bool isbf) {
    return isbf ? (float)((const bf16_t*)in)[j] : ((const float*)in)[j];
}
__device__ __forceinline__ bf16_t cvt_elem(const void* in, size_t j, bool isbf) {
    return isbf ? ((const bf16_t*)in)[j] : (bf16_t)((const float*)in)[j];
}
__device__ __forceinline__ int edge_src(const int* ei, int e, bool is64) {
    return clamp_node(is64 ? ei[2 * e] : ei[e]);
}
__device__ __forceinline__ int edge_dst(const int* ei, int e, bool is64) {
    return clamp_node(is64 ? ei[2 * NEDGE + 2 * e] : ei[NEDGE + e]);
}

// ---------------- prep_v: v_s/v_d[l][h][k] = sum_c Wg[l][k][h*128+c] * att[l][h][c] ----------------
__global__ __launch_bounds__(256) void prep_v(const void* x, const void* Wg,
                                              const void* aS, const void* aD,
                                              float* __restrict__ vS, float* __restrict__ vD) {
    bool isbf = wave_detect_bf16((const unsigned short*)x);
    int w = (int)((blockIdx.x * blockDim.x + threadIdx.x) >> 6);
    if (w >= LAYERS * DIM * NH * 2) return;
    int lane = threadIdx.x & 63;
    int sd = w & 1, h = (w >> 1) & 3, k = (w >> 3) & 127, l = w >> 10;
    const void* att = sd ? aD : aS;
    size_t wbase = (size_t)l * DIM * HD + (size_t)k * HD + h * DIM;
    size_t abase = (size_t)l * NH * DIM + (size_t)h * DIM;
    int c = 2 * lane;
    float p = raw_elem(Wg, wbase + c, isbf) * raw_elem(att, abase + c, isbf)
            + raw_elem(Wg, wbase + c + 1, isbf) * raw_elem(att, abase + c + 1, isbf);
#pragma unroll
    for (int msk = 1; msk < 64; msk <<= 1) p += __shfl_xor(p, msk);
    if (lane == 0) {
        float* dst = sd ? vD : vS;
        dst[l * HD + h * DIM + k] = p;
    }
}

// ---------------- canonicalization (+ hist fused as trailing blocks) ----------------
__global__ __launch_bounds__(256) void convert_hist(
        const void* x, const void* Wg, const void* W1, const void* W2,
        const void* bg, const void* b1, const void* b2, const void* n1, const void* n2,
        bf16_t* xb, bf16_t* WmixT, bf16_t* W1T, bf16_t* W2T,
        bf16_t* bgc, bf16_t* b1c, bf16_t* b2c, bf16_t* n1c, bf16_t* n2c,
        const int* ei, int* deg, int convBlocks) {
    const int NX  = N_NODES * DIM;
    const int NWG = LAYERS * DIM * HD;
    const int NW1 = LAYERS * DIM * DIM;
    const int NV  = LAYERS * DIM;
    if ((int)blockIdx.x >= convBlocks) {
        bool is64 = wave_detect_i64(ei);
        int e = ((int)blockIdx.x - convBlocks) * 256 + threadIdx.x;
        if (e < NEDGE) atomicAdd(&deg[edge_dst(ei, e, is64)], 1);
        return;
    }
    bool isbf = wave_detect_bf16((const unsigned short*)x);
    int i = blockIdx.x * blockDim.x + threadIdx.x;
    if (i < NX) { xb[i] = cvt_elem(x, i, isbf); return; }
    i -= NX;
    if (i < NWG) {   // WmixT[l][c][h*128+k] = Wg[l][k][h*128+c]
        int l = i / (DIM * HD);
        int rem = i - l * (DIM * HD);
        int c = rem / HD, kp = rem - c * HD;
        int h = kp >> 7, k = kp & 127;
        WmixT[i] = cvt_elem(Wg, (size_t)l * DIM * HD + (size_t)k * HD + h * DIM + c, isbf);
        return;
    }
    i -= NWG;
    if (i < NW1) {
        int l = i / (DIM * DIM);
        int rem = i - l * (DIM * DIM);
        int c = rem / DIM, k = rem - c * DIM;
        W1T[i] = cvt_elem(W1, (size_t)l * DIM * DIM + (size_t)k * DIM + c, isbf);
        return;
    }
    i -= NW1;
    if (i < NW1) {
        int l = i / (DIM * DIM);
        int rem = i - l * (DIM * DIM);
        int c = rem / DIM, k = rem - c * DIM;
        W2T[i] = cvt_elem(W2, (size_t)l * DIM * DIM + (size_t)k * DIM + c, isbf);
        return;
    }
    i -= NW1;
    if (i >= 5 * NV) return;
    int seg = i / NV, k = i - seg * NV;
    if (seg == 0) bgc[k] = cvt_elem(bg, k, isbf);
    else if (seg == 1) b1c[k] = cvt_elem(b1, k, isbf);
    else if (seg == 2) b2c[k] = cvt_elem(b2, k, isbf);
    else if (seg == 3) n1c[k] = cvt_elem(n1, k, isbf);
    else n2c[k] = cvt_elem(n2, k, isbf);
}

__global__ __launch_bounds__(1024) void scan_kernel(const int* __restrict__ deg,
                                                    int* __restrict__ row_ptr,
                                                    int* __restrict__ cursor) {
    __shared__ int wsum[16];
    __shared__ int carry_s;
    int tid = threadIdx.x, lane = tid & 63, wv = tid >> 6;
    if (tid == 0) { carry_s = 0; row_ptr[0] = 0; }
    __syncthreads();
    for (int base = 0; base < N_NODES; base += 1024) {
        int idx = base + tid;
        int v = (idx < N_NODES) ? deg[idx] : 0;
        int x = v;
#pragma unroll
        for (int off = 1; off < 64; off <<= 1) {
            int t = __shfl_up(x, off);
            if (lane >= off) x += t;
        }
        if (lane == 63) wsum[wv] = x;
        __syncthreads();
        if (wv == 0) {
            int s = (lane < 16) ? wsum[lane] : 0;
#pragma unroll
            for (int off = 1; off < 16; off <<= 1) {
                int t = __shfl_up(s, off);
                if (lane >= off) s += t;
            }
            if (lane < 16) wsum[lane] = s;
        }
        __syncthreads();
        int woff = (wv == 0) ? 0 : wsum[wv - 1];
        int c = carry_s;
        int incl = x + woff + c;
        if (idx < N_NODES) {
            row_ptr[idx + 1] = incl;
            cursor[idx] = incl - v;
        }
        __syncthreads();
        if (tid == 1023) carry_s = incl;
        __syncthreads();
    }
}

__global__ void fill_kernel(const int* __restrict__ ei, int* __restrict__ cursor,
                            int* __restrict__ csr_src) {
    bool is64 = wave_detect_i64(ei);
    int e = blockIdx.x * blockDim.x + threadIdx.x;
    if (e < NEDGE) {
        int d = edge_dst(ei, e, is64);
        int pos = atomicAdd(&cursor[d], 1);
        if ((unsigned)pos < (unsigned)NEDGE) csr_src[pos] = edge_src(ei, e, is64);
    }
}

// ---------------- asd_x8 (layer 0): a_s/a_d = x·v, x8 = fp8(x) ----------------
__global__ __launch_bounds__(256) void asd_x8(const bf16_t* __restrict__ xb,
                                              const float* __restrict__ vS,
                                              const float* __restrict__ vD,
                                              float* __restrict__ a_s,
                                              float* __restrict__ a_d,
                                              unsigned short* __restrict__ x8) {
    int n = (int)((blockIdx.x * blockDim.x + threadIdx.x) >> 6);
    if (n >= N_NODES) return;
    int lane = threadIdx.x & 63;
    int c = 2 * lane;
    bf16v2 xv = *reinterpret_cast<const bf16v2*>(xb + (size_t)n * DIM + c);
    float f0 = (float)xv[0], f1 = (float)xv[1];
    x8[n * 64 + lane] = enc_fp8_pair(f0, f1);
#pragma unroll
    for (int h = 0; h < NH; ++h) {
        float ps = f0 * vS[h * DIM + c] + f1 * vS[h * DIM + c + 1];
        float pd = f0 * vD[h * DIM + c] + f1 * vD[h * DIM + c + 1];
#pragma unroll
        for (int msk = 1; msk < 64; msk <<= 1) {
            ps += __shfl_xor(ps, msk);
            pd += __shfl_xor(pd, msk);
        }
        if (lane == 0) {
            a_s[n * 4 + h] = ps;
            a_d[n * 4 + h] = pd;
        }
    }
}

// ---------------- gat_gather: y[n, h*128+k] = (1/Z_h) sum_e alpha_eh * x8[s,k] ----------------
__global__ __launch_bounds__(256) void gat_gather(const int* __restrict__ row_ptr,
                                                  const int* __restrict__ csr_src,
                                                  const float* __restrict__ a_s,
                                                  const float* __restrict__ a_d,
                                                  const unsigned short* __restrict__ x8,
                                                  bf16_t* __restrict__ y) {
    __shared__ float4 wlds[4][DEGCAP];
    int n = (int)((blockIdx.x * blockDim.x + threadIdx.x) >> 6);
    if (n >= N_NODES) return;
    int lane = threadIdx.x & 63;
    int wv = threadIdx.x >> 6;
    int beg = row_ptr[n];
    int deg = row_ptr[n + 1] - beg;
    if (deg < 0) deg = 0;
    if (deg > NEDGE) deg = NEDGE;
    if (beg < 0) beg = 0;
    if (beg > NEDGE - deg) beg = NEDGE - deg;

    const float4* a_s4 = reinterpret_cast<const float4*>(a_s);
    const float4 adv = reinterpret_cast<const float4*>(a_d)[n];
    const float4 avs = a_s4[n];
    unsigned short pself = x8[n * 64 + lane];
    int s_reg = (lane < deg) ? clamp_node(csr_src[beg + lane]) : n;

    float4 ev_self = {leaky(avs.x + adv.x), leaky(avs.y + adv.y),
                      leaky(avs.z + adv.z), leaky(avs.w + adv.w)};
    float4 m4 = ev_self;
    for (int i = lane; i < deg; i += 64) {
        int s = (i == lane) ? s_reg : clamp_node(csr_src[beg + i]);
        float4 av = a_s4[s];
        float4 ev = {leaky(av.x + adv.x), leaky(av.y + adv.y),
                     leaky(av.z + adv.z), leaky(av.w + adv.w)};
        if (i < DEGCAP) wlds[wv][i] = ev;
        m4.x = fmaxf(m4.x, ev.x); m4.y = fmaxf(m4.y, ev.y);
        m4.z = fmaxf(m4.z, ev.z); m4.w = fmaxf(m4.w, ev.w);
    }
#pragma unroll
    for (int msk = 1; msk < 64; msk <<= 1) {
        m4.x = fmaxf(m4.x, __shfl_xor(m4.x, msk));
        m4.y = fmaxf(m4.y, __shfl_xor(m4.y, msk));
        m4.z = fmaxf(m4.z, __shfl_xor(m4.z, msk));
        m4.w = fmaxf(m4.w, __shfl_xor(m4.w, msk));
    }
    float4 s4 = {0.f, 0.f, 0.f, 0.f};
    for (int i = lane; i < deg; i += 64) {
        float4 ev;
        if (i < DEGCAP) ev = wlds[wv][i];
        else {
            int s = clamp_node(csr_src[beg + i]);
            float4 av = a_s4[s];
            ev = {leaky(av.x + adv.x), leaky(av.y + adv.y),
                  leaky(av.z + adv.z), leaky(av.w + adv.w)};
        }
        float4 ex = {__expf(ev.x - m4.x), __expf(ev.y - m4.y),
                     __expf(ev.z - m4.z), __expf(ev.w - m4.w)};
        if (i < DEGCAP) wlds[wv][i] = ex;
        s4.x += ex.x; s4.y += ex.y; s4.z += ex.z; s4.w += ex.w;
    }
#pragma unroll
    for (int msk = 1; msk < 64; msk <<= 1) {
        s4.x += __shfl_xor(s4.x, msk);
        s4.y += __shfl_xor(s4.y, msk);
        s4.z += __shfl_xor(s4.z, msk);
        s4.w += __shfl_xor(s4.w, msk);
    }
    float4 exs = {__expf(ev_self.x - m4.x), __expf(ev_self.y - m4.y),
                  __expf(ev_self.z - m4.z), __expf(ev_self.w - m4.w)};
    s4.x += exs.x; s4.y += exs.y; s4.z += exs.z; s4.w += exs.w;
    float4 ih4 = {1.f / s4.x, 1.f / s4.y, 1.f / s4.z, 1.f / s4.w};

    float acc[8];
    {
        f32v2 f = __builtin_amdgcn_cvt_pk_f32_fp8((int)pself, false);
        acc[0] = exs.x * f[0]; acc[1] = exs.x * f[1];
        acc[2] = exs.y * f[0]; acc[3] = exs.y * f[1];
        acc[4] = exs.z * f[0]; acc[5] = exs.z * f[1];
        acc[6] = exs.w * f[0]; acc[7] = exs.w * f[1];
    }
    for (int b0 = 0; b0 < deg; b0 += 4) {
        int cnt = deg - b0; if (cnt > 4) cnt = 4;
        unsigned short xe[4]; float4 w4[4];
#pragma unroll
        for (int u = 0; u < 4; ++u) {
            if (u < cnt) {
                int e = b0 + u;
                int s = (e < 64) ? __shfl(s_reg, e) : clamp_node(csr_src[beg + e]);
                xe[u] = x8[s * 64 + lane];
                if (e < DEGCAP) w4[u] = wlds[wv][e];
                else {
                    float4 av = a_s4[s];
                    w4[u] = {__expf(leaky(av.x + adv.x) - m4.x),
                             __expf(leaky(av.y + adv.y) - m4.y),
                             __expf(leaky(av.z + adv.z) - m4.z),
                             __expf(leaky(av.w + adv.w) - m4.w)};
                }
            }
        }
#pragma unroll
        for (int u = 0; u < 4; ++u) {
            if (u < cnt) {
                f32v2 f = __builtin_amdgcn_cvt_pk_f32_fp8((int)xe[u], false);
                acc[0] += w4[u].x * f[0]; acc[1] += w4[u].x * f[1];
                acc[2] += w4[u].y * f[0]; acc[3] += w4[u].y * f[1];
                acc[4] += w4[u].z * f[0]; acc[5] += w4[u].z * f[1];
                acc[6] += w4[u].w * f[0]; acc[7] += w4[u].w * f[1];
            }
        }
    }
    int c = 2 * lane;
#pragma unroll
    for (int h = 0; h < NH; ++h) {
        float ih = h == 0 ? ih4.x : h == 1 ? ih4.y : h == 2 ? ih4.z : ih4.w;
        bf16v2 o;
        o[0] = (bf16_t)(acc[h * 2 + 0] * ih);
        o[1] = (bf16_t)(acc[h * 2 + 1] * ih);
        *reinterpret_cast<bf16v2*>(y + (size_t)n * HD + h * DIM + c) = o;
    }
}

// ---------------- gemm_mix (split-K): xmid = rmsnorm(xb + 0.25*y@Wmix + bias_g, n1w) ----------------
// block = 4 waves = one 16x128 output tile; wave w does K-slice [128w, 128w+128).
__global__ __launch_bounds__(256) void gemm_mix(const bf16_t* __restrict__ y,
                                                const bf16_t* __restrict__ Bt,
                                                const bf16_t* __restrict__ bias,
                                                const bf16_t* __restrict__ res,
                                                const bf16_t* __restrict__ normw,
                                                bf16_t* __restrict__ xmid) {
    __shared__ float part[4][16][132];   // +4 pad: bank spread
    int tile = blockIdx.x;
    int wv = threadIdx.x >> 6;
    int lane = threadIdx.x & 63;
    int m = lane & 15, kq = lane >> 4;

    const bf16_t* Arow = y + (size_t)(tile * 16 + m) * HD + wv * 128 + kq * 8;
    bf16v8 a[4];
#pragma unroll
    for (int ks = 0; ks < 4; ++ks)
        a[ks] = *reinterpret_cast<const bf16v8*>(Arow + ks * 32);
    f32v4 acc[8];
#pragma unroll
    for (int t = 0; t < 8; ++t) acc[t] = (f32v4){0.f, 0.f, 0.f, 0.f};
    const bf16_t* Bbase = Bt + (size_t)m * HD + wv * 128 + kq * 8;
#pragma unroll
    for (int ks = 0; ks < 4; ++ks) {
#pragma unroll
        for (int t = 0; t < 8; ++t) {
            bf16v8 b = *reinterpret_cast<const bf16v8*>(Bbase + (size_t)t * 16 * HD + ks * 32);
            acc[t] = __builtin_amdgcn_mfma_f32_16x16x32_bf16(a[ks], b, acc[t], 0, 0, 0);
        }
    }
#pragma unroll
    for (int t = 0; t < 8; ++t) {
#pragma unroll
        for (int r = 0; r < 4; ++r)
            part[wv][kq * 4 + r][t * 16 + m] = acc[t][r];
    }
    __syncthreads();
    // final: thread -> (row = tid>>4, 8 cols at j*8)
    int row = threadIdx.x >> 4, j = threadIdx.x & 15;
    int gr = tile * 16 + row;
    bf16v8 rv = *reinterpret_cast<const bf16v8*>(res + (size_t)gr * DIM + j * 8);
    bf16v8 bv = *reinterpret_cast<const bf16v8*>(bias + j * 8);
    bf16v8 nwv = *reinterpret_cast<const bf16v8*>(normw + j * 8);
    float v[8];
    float ssq = 0.f;
#pragma unroll
    for (int u = 0; u < 8; ++u) {
        int col = j * 8 + u;
        float s = part[0][row][col] + part[1][row][col]
                + part[2][row][col] + part[3][row][col];
        float val = 0.25f * s + (float)bv[u] + (float)rv[u];
        v[u] = val;
        ssq += val * val;
    }
    ssq += __shfl_xor(ssq, 1); ssq += __shfl_xor(ssq, 2);
    ssq += __shfl_xor(ssq, 4); ssq += __shfl_xor(ssq, 8);
    float scale = rsqrtf(ssq * (1.f / 128.f) + EPS_RMS);
    bf16v8 ov;
#pragma unroll
    for (int u = 0; u < 8; ++u) ov[u] = (bf16_t)(v[u] * scale * (float)nwv[u]);
    *reinterpret_cast<bf16v8*>(xmid + (size_t)gr * DIM + j * 8) = ov;
}

// ---------------- fused FFN (+ next-layer asd/x8 for MODE 0) ----------------
template <int MODE>
__global__ __launch_bounds__(256) void ffn_fused(const bf16_t* __restrict__ A,
                                                 const bf16_t* __restrict__ B1t,
                                                 const bf16_t* __restrict__ b1,
                                                 const bf16_t* __restrict__ B2t,
                                                 const bf16_t* __restrict__ b2,
                                                 const bf16_t* __restrict__ nw,
                                                 void* __restrict__ Cout,
                                                 const float* __restrict__ vS,
                                                 const float* __restrict__ vD,
                                                 float* __restrict__ a_s,
                                                 float* __restrict__ a_d,
                                                 unsigned char* __restrict__ x8) {
    __shared__ bf16_t hl[4][16 * 136];
    int unit = (int)((blockIdx.x * blockDim.x + threadIdx.x) >> 6);
    if (unit >= NTILES) return;
    int lane = threadIdx.x & 63;
    int wv = threadIdx.x >> 6;
    int m = lane & 15, kq = lane >> 4;

    const bf16_t* Arow = A + (size_t)(unit * 16 + m) * DIM + kq * 8;
    bf16v8 a[4];
#pragma unroll
    for (int ks = 0; ks < 4; ++ks)
        a[ks] = *reinterpret_cast<const bf16v8*>(Arow + ks * 32);
    f32v4 acc[8];
#pragma unroll
    for (int t = 0; t < 8; ++t) acc[t] = (f32v4){0.f, 0.f, 0.f, 0.f};
    const bf16_t* Bb1 = B1t + (size_t)m * DIM + kq * 8;
#pragma unroll
    for (int ks = 0; ks < 4; ++ks) {
#pragma unroll
        for (int t = 0; t < 8; ++t) {
            bf16v8 b = *reinterpret_cast<const bf16v8*>(Bb1 + (size_t)t * 16 * DIM + ks * 32);
            acc[t] = __builtin_amdgcn_mfma_f32_16x16x32_bf16(a[ks], b, acc[t], 0, 0, 0);
        }
    }
#pragma unroll
    for (int t = 0; t < 8; ++t) {
        int col = t * 16 + m;
        float bv = (float)b1[col];
#pragma unroll
        for (int r = 0; r < 4; ++r) {
            float v = acc[t][r] + bv;
            v = v > 0.f ? v : 0.f;
            hl[wv][(kq * 4 + r) * 136 + col] = (bf16_t)v;
        }
    }
    bf16v8 a2[4];
#pragma unroll
    for (int ks = 0; ks < 4; ++ks)
        a2[ks] = *reinterpret_cast<const bf16v8*>(&hl[wv][m * 136 + ks * 32 + kq * 8]);
    f32v4 acc2[8];
#pragma unroll
    for (int t = 0; t < 8; ++t) acc2[t] = (f32v4){0.f, 0.f, 0.f, 0.f};
    const bf16_t* Bb2 = B2t + (size_t)m * DIM + kq * 8;
#pragma unroll
    for (int ks = 0; ks < 4; ++ks) {
#pragma unroll
        for (int t = 0; t < 8; ++t) {
            bf16v8 b = *reinterpret_cast<const bf16v8*>(Bb2 + (size_t)t * 16 * DIM + ks * 32);
            acc2[t] = __builtin_amdgcn_mfma_f32_16x16x32_bf16(a2[ks], b, acc2[t], 0, 0, 0);
        }
    }
    int growbase = unit * 16 + kq * 4;
    float vals[8][4];
    float ssq[4] = {0.f, 0.f, 0.f, 0.f};
#pragma unroll
    for (int t = 0; t < 8; ++t) {
        int col = t * 16 + m;
        float bv = (float)b2[col];
#pragma unroll
        for (int r = 0; r < 4; ++r) {
            float v = acc2[t][r] + bv + (float)A[(size_t)(growbase + r) * DIM + col];
            vals[t][r] = v;
            ssq[r] += v * v;
        }
    }
#pragma unroll
    for (int r = 0; r < 4; ++r) {
        float s = ssq[r];
        s += __shfl_xor(s, 1); s += __shfl_xor(s, 2);
        s += __shfl_xor(s, 4); s += __shfl_xor(s, 8);
        ssq[r] = rsqrtf(s * (1.f / 128.f) + EPS_RMS);
    }
    float ox[8][4];
#pragma unroll
    for (int t = 0; t < 8; ++t) {
        int col = t * 16 + m;
        float nwv = (float)nw[col];
#pragma unroll
        for (int r = 0; r < 4; ++r) {
            float o = vals[t][r] * ssq[r] * nwv;
            ox[t][r] = o;
            if (MODE == 1) ((float*)Cout)[(size_t)(growbase + r) * DIM + col] = o;
            else           ((bf16_t*)Cout)[(size_t)(growbase + r) * DIM + col] = (bf16_t)o;
        }
    }
    if (MODE == 0) {
#pragma unroll
        for (int t = 0; t < 8; ++t) {
            int col = t * 16 + m;
#pragma unroll
            for (int r = 0; r < 4; ++r)
                x8[(size_t)(growbase + r) * DIM + col] = enc_fp8(ox[t][r]);
        }
#pragma unroll
        for (int r = 0; r < 4; ++r) {
#pragma unroll
            for (int h = 0; h < NH; ++h) {
                float ps = 0.f, pd = 0.f;
#pragma unroll
                for (int t = 0; t < 8; ++t) {
                    int col = t * 16 + m;
                    ps += ox[t][r] * vS[h * DIM + col];
                    pd += ox[t][r] * vD[h * DIM + col];
                }
                ps += __shfl_xor(ps, 1); ps += __shfl_xor(ps, 2);
                ps += __shfl_xor(ps, 4); ps += __shfl_xor(ps, 8);
                pd += __shfl_xor(pd, 1); pd += __shfl_xor(pd, 2);
                pd += __shfl_xor(pd, 4); pd += __shfl_xor(pd, 8);
                if (m == 0) {
                    int row = growbase + r;
                    a_s[row * 4 + h] = ps;
                    a_d[row * 4 + h] = pd;
                }
            }
        }
    }
}

// ---------------- launch ----------------
extern "C" void kernel_launch(void* const* d_in, const int* in_sizes, int n_in,
                              void* d_out, int out_size, void* d_ws, size_t ws_size,
                              hipStream_t stream) {
    const void* x_in   = d_in[0];
    const void* W_gat  = d_in[1];
    const void* att_s  = d_in[2];
    const void* att_d  = d_in[3];
    const void* bias_g = d_in[4];
    const void* W1     = d_in[5];
    const void* b1     = d_in[6];
    const void* W2     = d_in[7];
    const void* b2     = d_in[8];
    const void* n1w    = d_in[9];
    const void* n2w    = d_in[10];
    const int*  ei     = (const int*)d_in[11];

    char* ws = (char*)d_ws;
    size_t off = 0;
    auto alloc = [&](size_t bytes) {
        void* p = ws + off;
        off = (off + bytes + 255) & ~(size_t)255;
        return p;
    };
    bf16_t* WmixT   = (bf16_t*)alloc((size_t)LAYERS * HD * DIM * 2);
    bf16_t* W1T     = (bf16_t*)alloc((size_t)LAYERS * DIM * DIM * 2);
    bf16_t* W2T     = (bf16_t*)alloc((size_t)LAYERS * DIM * DIM * 2);
    bf16_t* xb      = (bf16_t*)alloc((size_t)N_NODES * DIM * 2);
    bf16_t* y       = (bf16_t*)alloc((size_t)N_NODES * HD * 2);
    unsigned short* x8 = (unsigned short*)alloc((size_t)N_NODES * DIM);
    float*  vS      = (float*)alloc((size_t)LAYERS * HD * 4);
    float*  vD      = (float*)alloc((size_t)LAYERS * HD * 4);
    float*  a_s     = (float*)alloc((size_t)N_NODES * NH * 4);
    float*  a_d     = (float*)alloc((size_t)N_NODES * NH * 4);
    int*    deg     = (int*)alloc((size_t)N_NODES * 4);
    int*    cursor  = (int*)alloc((size_t)N_NODES * 4);
    int*    row_ptr = (int*)alloc((size_t)(N_NODES + 1) * 4);
    int*    csr     = (int*)alloc((size_t)NEDGE * 4);
    bf16_t* xmid    = (bf16_t*)alloc((size_t)N_NODES * DIM * 2);
    bf16_t* bgc     = (bf16_t*)alloc((size_t)LAYERS * DIM * 2);
    bf16_t* b1c     = (bf16_t*)alloc((size_t)LAYERS * DIM * 2);
    bf16_t* b2c     = (bf16_t*)alloc((size_t)LAYERS * DIM * 2);
    bf16_t* n1c     = (bf16_t*)alloc((size_t)LAYERS * DIM * 2);
    bf16_t* n2c     = (bf16_t*)alloc((size_t)LAYERS * DIM * 2);

    hipMemsetAsync(deg, 0, (size_t)N_NODES * 4, stream);

    prep_v<<<(LAYERS * DIM * NH * 2 * 64 + 255) / 256, 256, 0, stream>>>(
        x_in, W_gat, att_s, att_d, vS, vD);

    const int NTOT = N_NODES * DIM + LAYERS * DIM * HD + 2 * LAYERS * DIM * DIM
                   + 5 * LAYERS * DIM;
    const int convBlocks = (NTOT + 255) / 256;
    const int histBlocks = (NEDGE + 255) / 256;
    convert_hist<<<convBlocks + histBlocks, 256, 0, stream>>>(
        x_in, W_gat, W1, W2, bias_g, b1, b2, n1w, n2w,
        xb, WmixT, W1T, W2T, bgc, b1c, b2c, n1c, n2c,
        ei, deg, convBlocks);

    scan_kernel<<<1, 1024, 0, stream>>>(deg, row_ptr, cursor);
    fill_kernel<<<(NEDGE + 255) / 256, 256, 0, stream>>>(ei, cursor, csr);
    asd_x8<<<(N_NODES * 64 + 255) / 256, 256, 0, stream>>>(xb, vS, vD, a_s, a_d, x8);

    for (int l = 0; l < LAYERS; ++l) {
        gat_gather<<<(N_NODES * 64 + 255) / 256, 256, 0, stream>>>(
            row_ptr, csr, a_s, a_d, x8, y);
        gemm_mix<<<NTILES, 256, 0, stream>>>(
            y, WmixT + (size_t)l * HD * DIM, bgc + (size_t)l * DIM,
            xb, n1c + (size_t)l * DIM, xmid);
        if (l < LAYERS - 1) {
            ffn_fused<0><<<(NTILES * 64 + 255) / 256, 256, 0, stream>>>(
                xmid, W1T + (size_t)l * DIM * DIM, b1c + (size_t)l * DIM,
                W2T + (size_t)l * DIM * DIM, b2c + (size_t)l * DIM,
                n2c + (size_t)l * DIM, xb,
                vS + (size_t)(l + 1) * HD, vD + (size_t)(l + 1) * HD,
                a_s, a_d, (unsigned char*)x8);
        } else {
            ffn_fused<1><<<(NTILES * 64 + 255) / 256, 256, 0, stream>>>(
                xmid, W1T + (size_t)l * DIM * DIM, b1c + (size_t)l * DIM,
                W2T + (size_t)l * DIM * DIM, b2c + (size_t)l * DIM,
                n2c + (size_t)l * DIM, d_out,
                nullptr, nullptr, nullptr, nullptr, nullptr);
        }
    }
}

// Round 10
// 392.540 us; speedup vs baseline: 1.1071x; 1.0189x over previous
//
#include <hip/hip_runtime.h>
#include <hip/hip_bf16.h>

#define N_NODES 20000
#define NEDGE   320000
#define DIM     128
#define NH      4
#define HD      512   // NH*DIM
#define LAYERS  3
#define EPS_RMS 1.1920929e-07f
#define SLOPE   0.2f
#define DEGCAP  64
#define NTILES  (N_NODES >> 4)   // 1250

typedef __bf16 bf16_t;
typedef __bf16 bf16v2 __attribute__((ext_vector_type(2)));
typedef __bf16 bf16v8 __attribute__((ext_vector_type(8)));
typedef float  f32v4  __attribute__((ext_vector_type(4)));
typedef float  f32v2  __attribute__((ext_vector_type(2)));

__device__ __forceinline__ int clamp_node(int s) {
    return ((unsigned)s >= (unsigned)N_NODES) ? 0 : s;
}
__device__ __forceinline__ float leaky(float e) { return e > 0.f ? e : SLOPE * e; }
__device__ __forceinline__ unsigned char enc_fp8(float v) {
    int p = __builtin_amdgcn_cvt_pk_fp8_f32(v, v, 0, false);
    return (unsigned char)(p & 0xff);
}
__device__ __forceinline__ unsigned short enc_fp8_pair(float a, float b) {
    int p = __builtin_amdgcn_cvt_pk_fp8_f32(a, b, 0, false);
    return (unsigned short)(p & 0xffff);
}

// ---- per-wave dtype detection ----
__device__ __forceinline__ bool wave_detect_bf16(const unsigned short* xh) {
    int lane = threadIdx.x & 63;
    unsigned short hw = xh[2 * lane];
    int e = (hw >> 7) & 0xff;
    unsigned long long b = __ballot(e >= 96 && e <= 140);
    return __popcll(b) >= 48;
}
__device__ __forceinline__ bool wave_detect_i64(const int* ei) {
    int lane = threadIdx.x & 63;
    unsigned long long b = __ballot(ei[2 * lane + 1] != 0);
    return b == 0ULL;
}
__device__ __forceinline__ float raw_elem(const void* in, size_t j, bool isbf) {
    return isbf ? (float)((const bf16_t*)in)[j] : ((const float*)in)[j];
}
__device__ __forceinline__ bf16_t cvt_elem(const void* in, size_t j, bool isbf) {
    return isbf ? ((const bf16_t*)in)[j] : (bf16_t)((const float*)in)[j];
}
__device__ __forceinline__ int edge_src(const int* ei, int e, bool is64) {
    return clamp_node(is64 ? ei[2 * e] : ei[e]);
}
__device__ __forceinline__ int edge_dst(const int* ei, int e, bool is64) {
    return clamp_node(is64 ? ei[2 * NEDGE + 2 * e] : ei[NEDGE + e]);
}

// ---------------- prep_v: v_s/v_d[l][h][k] = sum_c Wg[l][k][h*128+c] * att[l][h][c] ----------------
__global__ __launch_bounds__(256) void prep_v(const void* x, const void* Wg,
                                              const void* aS, const void* aD,
                                              float* __restrict__ vS, float* __restrict__ vD) {
    bool isbf = wave_detect_bf16((const unsigned short*)x);
    int w = (int)((blockIdx.x * blockDim.x + threadIdx.x) >> 6);
    if (w >= LAYERS * DIM * NH * 2) return;
    int lane = threadIdx.x & 63;
    int sd = w & 1, h = (w >> 1) & 3, k = (w >> 3) & 127, l = w >> 10;
    const void* att = sd ? aD : aS;
    size_t wbase = (size_t)l * DIM * HD + (size_t)k * HD + h * DIM;
    size_t abase = (size_t)l * NH * DIM + (size_t)h * DIM;
    int c = 2 * lane;
    float p = raw_elem(Wg, wbase + c, isbf) * raw_elem(att, abase + c, isbf)
            + raw_elem(Wg, wbase + c + 1, isbf) * raw_elem(att, abase + c + 1, isbf);
#pragma unroll
    for (int msk = 1; msk < 64; msk <<= 1) p += __shfl_xor(p, msk);
    if (lane == 0) {
        float* dst = sd ? vD : vS;
        dst[l * HD + h * DIM + k] = p;
    }
}

// ---------------- mega: convert + hist + asd_x8 (layer-0 coefs from raw x) ----------------
__global__ __launch_bounds__(256) void mega_setup(
        const void* x, const void* Wg, const void* W1, const void* W2,
        const void* bg, const void* b1, const void* b2, const void* n1, const void* n2,
        bf16_t* xb, bf16_t* WmixT, bf16_t* W1T, bf16_t* W2T,
        bf16_t* bgc, bf16_t* b1c, bf16_t* b2c, bf16_t* n1c, bf16_t* n2c,
        const int* ei, int* deg,
        const float* vS, const float* vD,
        float* a_s, float* a_d, unsigned short* x8,
        int convBlocks, int histBlocks) {
    const int NX  = N_NODES * DIM;
    const int NWG = LAYERS * DIM * HD;
    const int NW1 = LAYERS * DIM * DIM;
    const int NV  = LAYERS * DIM;
    int b = (int)blockIdx.x;
    if (b >= convBlocks + histBlocks) {   // asd_x8 part: wave per node
        bool isbf = wave_detect_bf16((const unsigned short*)x);
        int lane = threadIdx.x & 63;
        int n = (b - convBlocks - histBlocks) * 4 + (int)(threadIdx.x >> 6);
        if (n >= N_NODES) return;
        int c = 2 * lane;
        float f0 = raw_elem(x, (size_t)n * DIM + c, isbf);
        float f1 = raw_elem(x, (size_t)n * DIM + c + 1, isbf);
        x8[n * 64 + lane] = enc_fp8_pair(f0, f1);
#pragma unroll
        for (int h = 0; h < NH; ++h) {
            float ps = f0 * vS[h * DIM + c] + f1 * vS[h * DIM + c + 1];
            float pd = f0 * vD[h * DIM + c] + f1 * vD[h * DIM + c + 1];
#pragma unroll
            for (int msk = 1; msk < 64; msk <<= 1) {
                ps += __shfl_xor(ps, msk);
                pd += __shfl_xor(pd, msk);
            }
            if (lane == 0) {
                a_s[n * 4 + h] = ps;
                a_d[n * 4 + h] = pd;
            }
        }
        return;
    }
    if (b >= convBlocks) {   // histogram
        bool is64 = wave_detect_i64(ei);
        int e = (b - convBlocks) * 256 + threadIdx.x;
        if (e < NEDGE) atomicAdd(&deg[edge_dst(ei, e, is64)], 1);
        return;
    }
    bool isbf = wave_detect_bf16((const unsigned short*)x);
    int i = b * 256 + threadIdx.x;
    if (i < NX) { xb[i] = cvt_elem(x, i, isbf); return; }
    i -= NX;
    if (i < NWG) {   // WmixT[l][c][h*128+k] = Wg[l][k][h*128+c]
        int l = i / (DIM * HD);
        int rem = i - l * (DIM * HD);
        int c = rem / HD, kp = rem - c * HD;
        int h = kp >> 7, k = kp & 127;
        WmixT[i] = cvt_elem(Wg, (size_t)l * DIM * HD + (size_t)k * HD + h * DIM + c, isbf);
        return;
    }
    i -= NWG;
    if (i < NW1) {
        int l = i / (DIM * DIM);
        int rem = i - l * (DIM * DIM);
        int c = rem / DIM, k = rem - c * DIM;
        W1T[i] = cvt_elem(W1, (size_t)l * DIM * DIM + (size_t)k * DIM + c, isbf);
        return;
    }
    i -= NW1;
    if (i < NW1) {
        int l = i / (DIM * DIM);
        int rem = i - l * (DIM * DIM);
        int c = rem / DIM, k = rem - c * DIM;
        W2T[i] = cvt_elem(W2, (size_t)l * DIM * DIM + (size_t)k * DIM + c, isbf);
        return;
    }
    i -= NW1;
    if (i >= 5 * NV) return;
    int seg = i / NV, k = i - seg * NV;
    if (seg == 0) bgc[k] = cvt_elem(bg, k, isbf);
    else if (seg == 1) b1c[k] = cvt_elem(b1, k, isbf);
    else if (seg == 2) b2c[k] = cvt_elem(b2, k, isbf);
    else if (seg == 3) n1c[k] = cvt_elem(n1, k, isbf);
    else n2c[k] = cvt_elem(n2, k, isbf);
}

__global__ __launch_bounds__(1024) void scan_kernel(const int* __restrict__ deg,
                                                    int* __restrict__ row_ptr,
                                                    int* __restrict__ cursor) {
    __shared__ int wsum[16];
    __shared__ int carry_s;
    int tid = threadIdx.x, lane = tid & 63, wv = tid >> 6;
    if (tid == 0) { carry_s = 0; row_ptr[0] = 0; }
    __syncthreads();
    for (int base = 0; base < N_NODES; base += 1024) {
        int idx = base + tid;
        int v = (idx < N_NODES) ? deg[idx] : 0;
        int x = v;
#pragma unroll
        for (int off = 1; off < 64; off <<= 1) {
            int t = __shfl_up(x, off);
            if (lane >= off) x += t;
        }
        if (lane == 63) wsum[wv] = x;
        __syncthreads();
        if (wv == 0) {
            int s = (lane < 16) ? wsum[lane] : 0;
#pragma unroll
            for (int off = 1; off < 16; off <<= 1) {
                int t = __shfl_up(s, off);
                if (lane >= off) s += t;
            }
            if (lane < 16) wsum[lane] = s;
        }
        __syncthreads();
        int woff = (wv == 0) ? 0 : wsum[wv - 1];
        int c = carry_s;
        int incl = x + woff + c;
        if (idx < N_NODES) {
            row_ptr[idx + 1] = incl;
            cursor[idx] = incl - v;
        }
        __syncthreads();
        if (tid == 1023) carry_s = incl;
        __syncthreads();
    }
}

__global__ void fill_kernel(const int* __restrict__ ei, int* __restrict__ cursor,
                            int* __restrict__ csr_src) {
    bool is64 = wave_detect_i64(ei);
    int e = blockIdx.x * blockDim.x + threadIdx.x;
    if (e < NEDGE) {
        int d = edge_dst(ei, e, is64);
        int pos = atomicAdd(&cursor[d], 1);
        if ((unsigned)pos < (unsigned)NEDGE) csr_src[pos] = edge_src(ei, e, is64);
    }
}

// ---------------- fused layer: gather -> mix -> FFN, one block = 16 nodes ----------------
// MODE 0: writes bf16 out + next-layer x8/a_s/a_d.  MODE 1: writes f32 d_out.
template <int MODE>
__global__ __launch_bounds__(256) void layer_fused(
        const int* __restrict__ row_ptr, const int* __restrict__ csr_src,
        const float* __restrict__ a_s, const float* __restrict__ a_d,
        const unsigned short* __restrict__ x8,
        const bf16_t* __restrict__ WmixT, const bf16_t* __restrict__ bg,
        const bf16_t* __restrict__ n1w, const bf16_t* __restrict__ xb,
        const bf16_t* __restrict__ W1T, const bf16_t* __restrict__ b1,
        const bf16_t* __restrict__ W2T, const bf16_t* __restrict__ b2,
        const bf16_t* __restrict__ n2w, void* __restrict__ out,
        const float* __restrict__ vS, const float* __restrict__ vD,
        float* __restrict__ a_s_n, float* __restrict__ a_d_n,
        unsigned char* __restrict__ x8_n) {
    __shared__ bf16_t ylds[16][520];    // y tile (stride 520: 16B-aligned rows)
    __shared__ bf16_t xm[16][136];      // xmid tile
    __shared__ bf16_t hh[16][136];      // h tile
    __shared__ float  ssq_p[16][4];     // per-wave row sumsq partials
    __shared__ float  asd_p[4][16][8];  // per-wave a_s/a_d partials
    __shared__ float4 wlds[4][DEGCAP];

    int tile = blockIdx.x;
    int wv = threadIdx.x >> 6;
    int lane = threadIdx.x & 63;
    const float4* a_s4 = reinterpret_cast<const float4*>(a_s);

    // ---- stage A: gather 4 nodes per wave ----
    for (int q = 0; q < 4; ++q) {
        int nl = wv * 4 + q;
        int n = tile * 16 + nl;
        int beg = row_ptr[n];
        int deg = row_ptr[n + 1] - beg;
        if (deg < 0) deg = 0;
        if (deg > NEDGE) deg = NEDGE;
        if (beg < 0) beg = 0;
        if (beg > NEDGE - deg) beg = NEDGE - deg;
        const float4 adv = reinterpret_cast<const float4*>(a_d)[n];
        const float4 avs = a_s4[n];
        unsigned short pself = x8[n * 64 + lane];
        int s_reg = (lane < deg) ? clamp_node(csr_src[beg + lane]) : n;

        float4 ev_self = {leaky(avs.x + adv.x), leaky(avs.y + adv.y),
                          leaky(avs.z + adv.z), leaky(avs.w + adv.w)};
        float4 m4 = ev_self;
        for (int i = lane; i < deg; i += 64) {
            int s = (i == lane) ? s_reg : clamp_node(csr_src[beg + i]);
            float4 av = a_s4[s];
            float4 ev = {leaky(av.x + adv.x), leaky(av.y + adv.y),
                         leaky(av.z + adv.z), leaky(av.w + adv.w)};
            if (i < DEGCAP) wlds[wv][i] = ev;
            m4.x = fmaxf(m4.x, ev.x); m4.y = fmaxf(m4.y, ev.y);
            m4.z = fmaxf(m4.z, ev.z); m4.w = fmaxf(m4.w, ev.w);
        }
#pragma unroll
        for (int msk = 1; msk < 64; msk <<= 1) {
            m4.x = fmaxf(m4.x, __shfl_xor(m4.x, msk));
            m4.y = fmaxf(m4.y, __shfl_xor(m4.y, msk));
            m4.z = fmaxf(m4.z, __shfl_xor(m4.z, msk));
            m4.w = fmaxf(m4.w, __shfl_xor(m4.w, msk));
        }
        float4 s4 = {0.f, 0.f, 0.f, 0.f};
        for (int i = lane; i < deg; i += 64) {
            float4 ev;
            if (i < DEGCAP) ev = wlds[wv][i];
            else {
                int s = clamp_node(csr_src[beg + i]);
                float4 av = a_s4[s];
                ev = {leaky(av.x + adv.x), leaky(av.y + adv.y),
                      leaky(av.z + adv.z), leaky(av.w + adv.w)};
            }
            float4 ex = {__expf(ev.x - m4.x), __expf(ev.y - m4.y),
                         __expf(ev.z - m4.z), __expf(ev.w - m4.w)};
            if (i < DEGCAP) wlds[wv][i] = ex;
            s4.x += ex.x; s4.y += ex.y; s4.z += ex.z; s4.w += ex.w;
        }
#pragma unroll
        for (int msk = 1; msk < 64; msk <<= 1) {
            s4.x += __shfl_xor(s4.x, msk);
            s4.y += __shfl_xor(s4.y, msk);
            s4.z += __shfl_xor(s4.z, msk);
            s4.w += __shfl_xor(s4.w, msk);
        }
        float4 exs = {__expf(ev_self.x - m4.x), __expf(ev_self.y - m4.y),
                      __expf(ev_self.z - m4.z), __expf(ev_self.w - m4.w)};
        s4.x += exs.x; s4.y += exs.y; s4.z += exs.z; s4.w += exs.w;
        float4 ih4 = {1.f / s4.x, 1.f / s4.y, 1.f / s4.z, 1.f / s4.w};

        float acc[8];
        {
            f32v2 f = __builtin_amdgcn_cvt_pk_f32_fp8((int)pself, false);
            acc[0] = exs.x * f[0]; acc[1] = exs.x * f[1];
            acc[2] = exs.y * f[0]; acc[3] = exs.y * f[1];
            acc[4] = exs.z * f[0]; acc[5] = exs.z * f[1];
            acc[6] = exs.w * f[0]; acc[7] = exs.w * f[1];
        }
        for (int b0 = 0; b0 < deg; b0 += 4) {
            int cnt = deg - b0; if (cnt > 4) cnt = 4;
            unsigned short xe[4]; float4 w4[4];
#pragma unroll
            for (int u = 0; u < 4; ++u) {
                if (u < cnt) {
                    int e = b0 + u;
                    int s = (e < 64) ? __shfl(s_reg, e) : clamp_node(csr_src[beg + e]);
                    xe[u] = x8[s * 64 + lane];
                    if (e < DEGCAP) w4[u] = wlds[wv][e];
                    else {
                        float4 av = a_s4[s];
                        w4[u] = {__expf(leaky(av.x + adv.x) - m4.x),
                                 __expf(leaky(av.y + adv.y) - m4.y),
                                 __expf(leaky(av.z + adv.z) - m4.z),
                                 __expf(leaky(av.w + adv.w) - m4.w)};
                    }
                }
            }
#pragma unroll
            for (int u = 0; u < 4; ++u) {
                if (u < cnt) {
                    f32v2 f = __builtin_amdgcn_cvt_pk_f32_fp8((int)xe[u], false);
                    acc[0] += w4[u].x * f[0]; acc[1] += w4[u].x * f[1];
                    acc[2] += w4[u].y * f[0]; acc[3] += w4[u].y * f[1];
                    acc[4] += w4[u].z * f[0]; acc[5] += w4[u].z * f[1];
                    acc[6] += w4[u].w * f[0]; acc[7] += w4[u].w * f[1];
                }
            }
        }
        int c = 2 * lane;
#pragma unroll
        for (int h = 0; h < NH; ++h) {
            float ih = h == 0 ? ih4.x : h == 1 ? ih4.y : h == 2 ? ih4.z : ih4.w;
            bf16v2 o;
            o[0] = (bf16_t)(acc[h * 2 + 0] * ih);
            o[1] = (bf16_t)(acc[h * 2 + 1] * ih);
            *reinterpret_cast<bf16v2*>(&ylds[nl][h * DIM + c]) = o;
        }
    }
    __syncthreads();

    // ---- stage B: mix (N-split: wave wv computes cols [32wv, 32wv+32), K=512) ----
    int m = lane & 15, kq = lane >> 4;
    f32v4 accm[2];
    accm[0] = (f32v4){0.f, 0.f, 0.f, 0.f};
    accm[1] = (f32v4){0.f, 0.f, 0.f, 0.f};
    {
        const bf16_t* Bc = WmixT + (size_t)(32 * wv + m) * HD + kq * 8;
#pragma unroll
        for (int kk = 0; kk < 16; ++kk) {
            bf16v8 a = *reinterpret_cast<const bf16v8*>(&ylds[m][kk * 32 + kq * 8]);
#pragma unroll
            for (int tt = 0; tt < 2; ++tt) {
                bf16v8 b = *reinterpret_cast<const bf16v8*>(Bc + (size_t)tt * 16 * HD + kk * 32);
                accm[tt] = __builtin_amdgcn_mfma_f32_16x16x32_bf16(a, b, accm[tt], 0, 0, 0);
            }
        }
    }
    float vals[2][4];
    {
        float sp[4] = {0.f, 0.f, 0.f, 0.f};
#pragma unroll
        for (int tt = 0; tt < 2; ++tt) {
            int col = 32 * wv + tt * 16 + m;
            float bv = (float)bg[col];
#pragma unroll
            for (int r = 0; r < 4; ++r) {
                int gr = tile * 16 + kq * 4 + r;
                float v = 0.25f * accm[tt][r] + bv + (float)xb[(size_t)gr * DIM + col];
                vals[tt][r] = v;
                sp[r] += v * v;
            }
        }
#pragma unroll
        for (int r = 0; r < 4; ++r) {
            sp[r] += __shfl_xor(sp[r], 1); sp[r] += __shfl_xor(sp[r], 2);
            sp[r] += __shfl_xor(sp[r], 4); sp[r] += __shfl_xor(sp[r], 8);
            if (m == r) ssq_p[kq * 4 + r][wv] = sp[r];
        }
    }
    __syncthreads();
    {
#pragma unroll
        for (int r = 0; r < 4; ++r) {
            int row = kq * 4 + r;
            float s = ssq_p[row][0] + ssq_p[row][1] + ssq_p[row][2] + ssq_p[row][3];
            float scale = rsqrtf(s * (1.f / 128.f) + EPS_RMS);
#pragma unroll
            for (int tt = 0; tt < 2; ++tt) {
                int col = 32 * wv + tt * 16 + m;
                xm[row][col] = (bf16_t)(vals[tt][r] * scale * (float)n1w[col]);
            }
        }
    }
    __syncthreads();

    // ---- stage C: FFN (N-split) ----
    f32v4 acc1[2];
    acc1[0] = (f32v4){0.f, 0.f, 0.f, 0.f};
    acc1[1] = (f32v4){0.f, 0.f, 0.f, 0.f};
#pragma unroll
    for (int ks = 0; ks < 4; ++ks) {
        bf16v8 a = *reinterpret_cast<const bf16v8*>(&xm[m][ks * 32 + kq * 8]);
#pragma unroll
        for (int tt = 0; tt < 2; ++tt) {
            bf16v8 b = *reinterpret_cast<const bf16v8*>(
                W1T + (size_t)((2 * wv + tt) * 16 + m) * DIM + ks * 32 + kq * 8);
            acc1[tt] = __builtin_amdgcn_mfma_f32_16x16x32_bf16(a, b, acc1[tt], 0, 0, 0);
        }
    }
#pragma unroll
    for (int tt = 0; tt < 2; ++tt) {
        int col = 32 * wv + tt * 16 + m;
        float bv = (float)b1[col];
#pragma unroll
        for (int r = 0; r < 4; ++r) {
            float v = acc1[tt][r] + bv;
            hh[kq * 4 + r][col] = (bf16_t)(v > 0.f ? v : 0.f);
        }
    }
    __syncthreads();
    f32v4 acc2[2];
    acc2[0] = (f32v4){0.f, 0.f, 0.f, 0.f};
    acc2[1] = (f32v4){0.f, 0.f, 0.f, 0.f};
#pragma unroll
    for (int ks = 0; ks < 4; ++ks) {
        bf16v8 a = *reinterpret_cast<const bf16v8*>(&hh[m][ks * 32 + kq * 8]);
#pragma unroll
        for (int tt = 0; tt < 2; ++tt) {
            bf16v8 b = *reinterpret_cast<const bf16v8*>(
                W2T + (size_t)((2 * wv + tt) * 16 + m) * DIM + ks * 32 + kq * 8);
            acc2[tt] = __builtin_amdgcn_mfma_f32_16x16x32_bf16(a, b, acc2[tt], 0, 0, 0);
        }
    }
    float vals2[2][4];
    {
        float sp[4] = {0.f, 0.f, 0.f, 0.f};
#pragma unroll
        for (int tt = 0; tt < 2; ++tt) {
            int col = 32 * wv + tt * 16 + m;
            float bv = (float)b2[col];
#pragma unroll
            for (int r = 0; r < 4; ++r) {
                float v = acc2[tt][r] + bv + (float)xm[kq * 4 + r][col];
                vals2[tt][r] = v;
                sp[r] += v * v;
            }
        }
#pragma unroll
        for (int r = 0; r < 4; ++r) {
            sp[r] += __shfl_xor(sp[r], 1); sp[r] += __shfl_xor(sp[r], 2);
            sp[r] += __shfl_xor(sp[r], 4); sp[r] += __shfl_xor(sp[r], 8);
            if (m == r) ssq_p[kq * 4 + r][wv] = sp[r];
        }
    }
    __syncthreads();
    float o2[2][4];
#pragma unroll
    for (int r = 0; r < 4; ++r) {
        int row = kq * 4 + r;
        int gr = tile * 16 + row;
        float s = ssq_p[row][0] + ssq_p[row][1] + ssq_p[row][2] + ssq_p[row][3];
        float scale = rsqrtf(s * (1.f / 128.f) + EPS_RMS);
#pragma unroll
        for (int tt = 0; tt < 2; ++tt) {
            int col = 32 * wv + tt * 16 + m;
            float o = vals2[tt][r] * scale * (float)n2w[col];
            o2[tt][r] = o;
            if (MODE == 1) ((float*)out)[(size_t)gr * DIM + col] = o;
            else {
                ((bf16_t*)out)[(size_t)gr * DIM + col] = (bf16_t)o;
                x8_n[(size_t)gr * DIM + col] = enc_fp8(o);
            }
        }
    }
    if (MODE == 0) {
        // next-layer a_s/a_d: per (row,h) cross-lane + cross-wave reduction
        float vs0[NH], vs1[NH], vd0[NH], vd1[NH];
        int col0 = 32 * wv + m, col1 = col0 + 16;
#pragma unroll
        for (int h = 0; h < NH; ++h) {
            vs0[h] = vS[h * DIM + col0]; vs1[h] = vS[h * DIM + col1];
            vd0[h] = vD[h * DIM + col0]; vd1[h] = vD[h * DIM + col1];
        }
#pragma unroll
        for (int r = 0; r < 4; ++r) {
#pragma unroll
            for (int h = 0; h < NH; ++h) {
                float ps = o2[0][r] * vs0[h] + o2[1][r] * vs1[h];
                float pd = o2[0][r] * vd0[h] + o2[1][r] * vd1[h];
                ps += __shfl_xor(ps, 1); ps += __shfl_xor(ps, 2);
                ps += __shfl_xor(ps, 4); ps += __shfl_xor(ps, 8);
                pd += __shfl_xor(pd, 1); pd += __shfl_xor(pd, 2);
                pd += __shfl_xor(pd, 4); pd += __shfl_xor(pd, 8);
                if (m == r * 4 + h) {
                    asd_p[wv][kq * 4 + r][h * 2 + 0] = ps;
                    asd_p[wv][kq * 4 + r][h * 2 + 1] = pd;
                }
            }
        }
        __syncthreads();
        int t = threadIdx.x;
        if (t < 128) {
            int row = t >> 3, idx = t & 7;
            float s = asd_p[0][row][idx] + asd_p[1][row][idx]
                    + asd_p[2][row][idx] + asd_p[3][row][idx];
            int gr = tile * 16 + row;
            if (idx & 1) a_d_n[gr * 4 + (idx >> 1)] = s;
            else         a_s_n[gr * 4 + (idx >> 1)] = s;
        }
    }
}

// ---------------- launch ----------------
extern "C" void kernel_launch(void* const* d_in, const int* in_sizes, int n_in,
                              void* d_out, int out_size, void* d_ws, size_t ws_size,
                              hipStream_t stream) {
    const void* x_in   = d_in[0];
    const void* W_gat  = d_in[1];
    const void* att_s  = d_in[2];
    const void* att_d  = d_in[3];
    const void* bias_g = d_in[4];
    const void* W1     = d_in[5];
    const void* b1     = d_in[6];
    const void* W2     = d_in[7];
    const void* b2     = d_in[8];
    const void* n1w    = d_in[9];
    const void* n2w    = d_in[10];
    const int*  ei     = (const int*)d_in[11];

    char* ws = (char*)d_ws;
    size_t off = 0;
    auto alloc = [&](size_t bytes) {
        void* p = ws + off;
        off = (off + bytes + 255) & ~(size_t)255;
        return p;
    };
    bf16_t* WmixT   = (bf16_t*)alloc((size_t)LAYERS * HD * DIM * 2);
    bf16_t* W1T     = (bf16_t*)alloc((size_t)LAYERS * DIM * DIM * 2);
    bf16_t* W2T     = (bf16_t*)alloc((size_t)LAYERS * DIM * DIM * 2);
    bf16_t* xb      = (bf16_t*)alloc((size_t)N_NODES * DIM * 2);
    unsigned short* x8a = (unsigned short*)alloc((size_t)N_NODES * DIM);
    unsigned short* x8b = (unsigned short*)alloc((size_t)N_NODES * DIM);
    float*  vS      = (float*)alloc((size_t)LAYERS * HD * 4);
    float*  vD      = (float*)alloc((size_t)LAYERS * HD * 4);
    float*  a_sA    = (float*)alloc((size_t)N_NODES * NH * 4);
    float*  a_dA    = (float*)alloc((size_t)N_NODES * NH * 4);
    float*  a_sB    = (float*)alloc((size_t)N_NODES * NH * 4);
    float*  a_dB    = (float*)alloc((size_t)N_NODES * NH * 4);
    int*    deg     = (int*)alloc((size_t)N_NODES * 4);
    int*    cursor  = (int*)alloc((size_t)N_NODES * 4);
    int*    row_ptr = (int*)alloc((size_t)(N_NODES + 1) * 4);
    int*    csr     = (int*)alloc((size_t)NEDGE * 4);
    bf16_t* bgc     = (bf16_t*)alloc((size_t)LAYERS * DIM * 2);
    bf16_t* b1c     = (bf16_t*)alloc((size_t)LAYERS * DIM * 2);
    bf16_t* b2c     = (bf16_t*)alloc((size_t)LAYERS * DIM * 2);
    bf16_t* n1c     = (bf16_t*)alloc((size_t)LAYERS * DIM * 2);
    bf16_t* n2c     = (bf16_t*)alloc((size_t)LAYERS * DIM * 2);

    hipMemsetAsync(deg, 0, (size_t)N_NODES * 4, stream);

    prep_v<<<(LAYERS * DIM * NH * 2 * 64 + 255) / 256, 256, 0, stream>>>(
        x_in, W_gat, att_s, att_d, vS, vD);

    const int NTOT = N_NODES * DIM + LAYERS * DIM * HD + 2 * LAYERS * DIM * DIM
                   + 5 * LAYERS * DIM;
    const int convBlocks = (NTOT + 255) / 256;
    const int histBlocks = (NEDGE + 255) / 256;
    const int asdBlocks  = (N_NODES + 3) / 4;
    mega_setup<<<convBlocks + histBlocks + asdBlocks, 256, 0, stream>>>(
        x_in, W_gat, W1, W2, bias_g, b1, b2, n1w, n2w,
        xb, WmixT, W1T, W2T, bgc, b1c, b2c, n1c, n2c,
        ei, deg, vS, vD, a_sA, a_dA, x8a, convBlocks, histBlocks);

    scan_kernel<<<1, 1024, 0, stream>>>(deg, row_ptr, cursor);
    fill_kernel<<<(NEDGE + 255) / 256, 256, 0, stream>>>(ei, cursor, csr);

    unsigned short* x8cur[2] = {x8a, x8b};
    float* asCur[2] = {a_sA, a_sB};
    float* adCur[2] = {a_dA, a_dB};
    for (int l = 0; l < LAYERS; ++l) {
        int ci = l & 1, ni = (l + 1) & 1;
        if (l < LAYERS - 1) {
            layer_fused<0><<<NTILES, 256, 0, stream>>>(
                row_ptr, csr, asCur[ci], adCur[ci], x8cur[ci],
                WmixT + (size_t)l * HD * DIM, bgc + (size_t)l * DIM,
                n1c + (size_t)l * DIM, xb,
                W1T + (size_t)l * DIM * DIM, b1c + (size_t)l * DIM,
                W2T + (size_t)l * DIM * DIM, b2c + (size_t)l * DIM,
                n2c + (size_t)l * DIM, xb,
                vS + (size_t)(l + 1) * HD, vD + (size_t)(l + 1) * HD,
                asCur[ni], adCur[ni], (unsigned char*)x8cur[ni]);
        } else {
            layer_fused<1><<<NTILES, 256, 0, stream>>>(
                row_ptr, csr, asCur[ci], adCur[ci], x8cur[ci],
                WmixT + (size_t)l * HD * DIM, bgc + (size_t)l * DIM,
                n1c + (size_t)l * DIM, xb,
                W1T + (size_t)l * DIM * DIM, b1c + (size_t)l * DIM,
                W2T + (size_t)l * DIM * DIM, b2c + (size_t)l * DIM,
                n2c + (size_t)l * DIM, d_out,
                nullptr, nullptr, nullptr, nullptr, nullptr);
        }
    }
}